// Round 1
// baseline (434.703 us; speedup 1.0000x reference)
//
#include <hip/hip_runtime.h>

#define TABLE_SIZE 4096
#define BLOCK 256

__global__ __launch_bounds__(BLOCK) void secgelu_kernel(
    const float* __restrict__ x, const float* __restrict__ table,
    float* __restrict__ out, int n4, int n)
{
    __shared__ float lds_table[TABLE_SIZE];
    // Stage the 16 KB table into LDS (coalesced, 16 iters of 256 threads).
    #pragma unroll
    for (int i = threadIdx.x; i < TABLE_SIZE; i += BLOCK)
        lds_table[i] = table[i];
    __syncthreads();

    const float4* __restrict__ x4 = (const float4*)x;
    float4* __restrict__ o4 = (float4*)out;

    const float inv_ydiv = 1.0f / 64.0f;   // Y_DIV = 2^16 / 2^10 = 64 (exact)
    int stride = gridDim.x * BLOCK;

    for (int idx = blockIdx.x * BLOCK + threadIdx.x; idx < n4; idx += stride) {
        float4 v = x4[idx];
        float4 r;
        float* vp = (float*)&v;
        float* rp = (float*)&r;
        #pragma unroll
        for (int k = 0; k < 4; ++k) {
            float xv = vp[k];
            // X = round-half-even(x * 2^16): rintf in default RN mode == np.round
            float X = rintf(xv * 65536.0f);
            // y = floor(X / 64): exact (X integral, /64 is exponent shift)
            float y = floorf(X * inv_ydiv);
            bool  d = (y >= 0.0f);
            float a = fabsf(y);                  // a = 2*d*y - y = |y|
            a = fminf(a, (float)(TABLE_SIZE - 1)); // clamp to table
            int   c = (int)a;
            rp[k] = (d ? xv : 0.0f) - lds_table[c];
        }
        o4[idx] = r;
    }

    // Tail (n not divisible by 4) — n = 4*4096*4096 here so this is dead,
    // but kept for safety; only the first few threads of block 0 run it.
    int tail_start = n4 * 4;
    int t = tail_start + (int)(blockIdx.x * BLOCK + threadIdx.x);
    if (blockIdx.x == 0 && t < n) {
        float xv = x[t];
        float X = rintf(xv * 65536.0f);
        float y = floorf(X * inv_ydiv);
        bool  d = (y >= 0.0f);
        float a = fminf(fabsf(y), (float)(TABLE_SIZE - 1));
        out[t] = (d ? xv : 0.0f) - lds_table[(int)a];
    }
}

extern "C" void kernel_launch(void* const* d_in, const int* in_sizes, int n_in,
                              void* d_out, int out_size, void* d_ws, size_t ws_size,
                              hipStream_t stream) {
    const float* x     = (const float*)d_in[0];
    const float* table = (const float*)d_in[1];
    float* out = (float*)d_out;
    int n  = in_sizes[0];
    int n4 = n / 4;

    // 8 blocks/CU * 256 CUs = 2048 blocks; each thread handles ~32 float4s.
    int blocks = 2048;
    secgelu_kernel<<<blocks, BLOCK, 0, stream>>>(x, table, out, n4, n);
}